// Round 8
// baseline (417.282 us; speedup 1.0000x reference)
//
#include <hip/hip_runtime.h>
#include <hip/hip_bf16.h>
#include <type_traits>

constexpr int B_ = 8, C_ = 256, P_ = 64, H_ = 64, W_ = 64, HW_ = 4096;

typedef __attribute__((ext_vector_type(8))) short short8;   // 8 bf16
typedef __attribute__((ext_vector_type(4))) short short4v;  // 4 bf16 (8 B)
typedef __attribute__((ext_vector_type(4))) float f32x4;

__device__ __forceinline__ short bfbits(float f) {
    __hip_bfloat16 h = __float2bfloat16(f);
    return *reinterpret_cast<short*>(&h);
}
__device__ __forceinline__ float bf2f(short s) {
    __hip_bfloat16 h = *reinterpret_cast<__hip_bfloat16*>(&s);
    return (float)h;
}

// async global->LDS, 16B per lane; dst must be wave-uniform base (HW adds lane*16)
#define GLL16(gsrc, ldst)                                                      \
    __builtin_amdgcn_global_load_lds(                                         \
        (const __attribute__((address_space(1))) void*)(gsrc),                \
        (__attribute__((address_space(3))) void*)(ldst), 16, 0, 0)

// ---------------------------------------------------------------------------
// Fragment-linear packed layouts (one wave-load = base + lane*16, contiguous):
//   xtP/xcP [b][tile16][kc2][lane64]x16B : chunk = x[row=tile*16+lm][p=kc*32+lq*8..+8]
//   xbP     [b][g128][ct16][lane64]x16B  : chunk = xb[c=ct*16+lm][m=g*32+lq*8..+8]
//   wbP     [tap9][cb8][cot16][lane64]x16B: chunk = w[co=cot*16+lm][ci=cb*32+lq*8..+8]
// ---------------------------------------------------------------------------

// K0: weight prep, fp32 OIHW -> fragment-linear bf16 wbP. 288 blocks.
__global__ __launch_bounds__(256) void k_prep_w(
    const float* __restrict__ w, short8* __restrict__ wbP)
{
    const int idx = blockIdx.x * 256 + threadIdx.x;      // < 9*8*16*64 = 73728
    const int lane = idx & 63, cot = (idx >> 6) & 15;
    const int cb = (idx >> 10) & 7, tap = idx >> 13;
    const int lm = lane & 15, lq = lane >> 4;
    const int co = cot * 16 + lm, ci0 = cb * 32 + lq * 8;
    short8 v;
#pragma unroll
    for (int k = 0; k < 8; ++k)
        v[k] = bfbits(w[(co * 256 + ci0 + k) * 9 + tap]);
    wbP[idx] = v;
}

// K0c: fp32 [B][C][HW] -> bf16 same-order copy (conv3x3 staging input).
// 2048 blocks; thread: 4 float4 loads -> 2 short8 stores (16 elems).
__global__ __launch_bounds__(256) void k_cvt_bf16(
    const float* __restrict__ x, short8* __restrict__ xB)
{
    const size_t i = ((size_t)blockIdx.x * 256 + threadIdx.x) * 16;
    short8 o[2];
#pragma unroll
    for (int q = 0; q < 2; ++q) {
#pragma unroll
        for (int j = 0; j < 2; ++j) {
            const float4 v = *reinterpret_cast<const float4*>(&x[i + q * 8 + j * 4]);
            o[q][j * 4 + 0] = bfbits(v.x);
            o[q][j * 4 + 1] = bfbits(v.y);
            o[q][j * 4 + 2] = bfbits(v.z);
            o[q][j * 4 + 3] = bfbits(v.w);
        }
    }
    short8* dp = (short8*)&xB[i >> 3];
    dp[0] = o[0];
    dp[1] = o[1];
}

// K0b: xb [B][C][HW] bf16 -> fragment-linear xbP. 4096 blocks.
__global__ __launch_bounds__(256) void k_pack_xb(
    const __hip_bfloat16* __restrict__ xb, short8* __restrict__ xbP)
{
    const int tid = blockIdx.x * 256 + threadIdx.x;
    const int lane = tid & 63, wid = tid >> 6;           // wid < 8*128*16
    const int ct = wid & 15, g = (wid >> 4) & 127, b = wid >> 11;
    const int c = ct * 16 + (lane >> 2);
    const int mo = g * 32 + (lane & 3) * 8;
    const short8 v = *reinterpret_cast<const short8*>(
        &xb[((size_t)(b * 256 + c)) * HW_ + mo]);
    xbP[(size_t)wid * 64 + (lane & 3) * 16 + (lane >> 2)] = v;
}

// ---------------------------------------------------------------------------
// K1: 1x1 convs. R14: BOTH convs merged per block (x read once for the pair:
// x traffic 8x -> 4x of tensor). Grid 16x4x8 (pq only). Weight loads are
// lane-uniform -> scalar path. Epilogue writes hi/lo bf16 fragment-linear.
// ---------------------------------------------------------------------------
__global__ __launch_bounds__(256) void k_conv1x1(
    const float* __restrict__ x,
    const float* __restrict__ w_top, const float* __restrict__ b_top,
    const float* __restrict__ w_cen, const float* __restrict__ b_cen,
    short8* __restrict__ xtPh, short8* __restrict__ xtPl,
    short8* __restrict__ xcPh, short8* __restrict__ xcPl)
{
    const int b = blockIdx.z;
    const int n = blockIdx.x * 256 + threadIdx.x;
    const int pq = blockIdx.y;                  // 0..3
    const int p0 = pq * 16;

    const float* xp = x + (size_t)b * C_ * HW_ + n;
    float acc0[16], acc1[16];
#pragma unroll
    for (int p = 0; p < 16; ++p) { acc0[p] = 0.f; acc1[p] = 0.f; }

    for (int c = 0; c < C_; c += 4) {
        const float xv0 = xp[(size_t)(c + 0) * HW_];
        const float xv1 = xp[(size_t)(c + 1) * HW_];
        const float xv2 = xp[(size_t)(c + 2) * HW_];
        const float xv3 = xp[(size_t)(c + 3) * HW_];
#pragma unroll
        for (int p = 0; p < 16; ++p) {
            const float4 wv0 = *reinterpret_cast<const float4*>(&w_top[(p0 + p) * C_ + c]);
            const float4 wv1 = *reinterpret_cast<const float4*>(&w_cen[(p0 + p) * C_ + c]);
            float a0 = acc0[p], a1 = acc1[p];
            a0 = fmaf(wv0.x, xv0, a0);  a1 = fmaf(wv1.x, xv0, a1);
            a0 = fmaf(wv0.y, xv1, a0);  a1 = fmaf(wv1.y, xv1, a1);
            a0 = fmaf(wv0.z, xv2, a0);  a1 = fmaf(wv1.z, xv2, a1);
            a0 = fmaf(wv0.w, xv3, a0);  a1 = fmaf(wv1.w, xv3, a1);
            acc0[p] = a0;  acc1[p] = a1;
        }
    }
    const int nt = n >> 4, lmn = n & 15;
    const size_t obase = ((size_t)(b * 256 + nt) * 2 + (pq >> 1)) * 64 + lmn;
#pragma unroll
    for (int jj = 0; jj < 2; ++jj) {
        short8 vh0, vl0, vh1, vl1;
#pragma unroll
        for (int k = 0; k < 8; ++k) {
            const float v0 = acc0[jj * 8 + k] + b_top[p0 + jj * 8 + k];
            const short hb0 = bfbits(v0);
            vh0[k] = hb0;
            vl0[k] = bfbits(v0 - bf2f(hb0));
            const float v1 = acc1[jj * 8 + k] + b_cen[p0 + jj * 8 + k];
            const short hb1 = bfbits(v1);
            vh1[k] = hb1;
            vl1[k] = bfbits(v1 - bf2f(hb1));
        }
        const size_t idx = obase + (size_t)(((pq & 1) * 2 + jj) * 16);
        xtPh[idx] = vh0;
        xtPl[idx] = vl0;
        xcPh[idx] = vh1;
        xcPl[idx] = vl1;
    }
}

// ---------------------------------------------------------------------------
// K2/K5: 3x3 conv as implicit GEMM, bf16 MFMA. R14: double-buffered LDS with
// T14 async reg-staging — per cb: ISSUE next-cb global loads, run 9 taps on
// current buffer (load latency hides under MFMAs), ds_write other buffer,
// ONE barrier. (R13 was: barrier, serial loads+writes, barrier, taps.)
// Grid 512 1D, b==XCD, 512-thread blocks, 2 blocks/CU. LDS 31.7 KB.
// ---------------------------------------------------------------------------
template <typename OT>
__global__ __launch_bounds__(512, 4) void k_conv3x3_mfma(
    const short* __restrict__ xin, const short8* __restrict__ wbP,
    const float* __restrict__ bias, OT* __restrict__ out)
{
    __shared__ __align__(16) short Xs[2][3][66][40];
    const int lin = blockIdx.x;                 // 0..511
    const int b = lin & 7, h = lin >> 3;        // b == XCD
    const int t = threadIdx.x;
    const int wave = t >> 6, lane = t & 63;
    const int lm = lane & 15, lq = lane >> 4;
    const int cobase = wave * 32;
    const int cot0 = wave * 2;                  // co-tile index base (co/16)

    f32x4 acc[4][2];   // [n_tile][co_tile]
#pragma unroll
    for (int i = 0; i < 4; ++i)
#pragma unroll
        for (int j = 0; j < 2; ++j) acc[i][j] = f32x4{0.f, 0.f, 0.f, 0.f};

    if (t < 384) {   // zero w-halo columns of BOTH buffers once
        const int bufi = t / 192, rem = t % 192;
        const int r = rem >> 6, cc = rem & 31, side = (rem >> 5) & 1;
        Xs[bufi][r][side ? 65 : 0][cc] = 0;
    }

    const short* xbase = xin + (size_t)b * C_ * HW_;

    // staging decode (fixed per thread): idx -> (r, ci, wq)
    short4v pv[3];
    auto gload = [&](int cb) {
        const int ci0 = cb * 32;
#pragma unroll
        for (int it = 0; it < 3; ++it) {
            const int idx = it * 512 + t;
            const int r = idx >> 9, ci = (idx >> 4) & 31, wq = idx & 15;
            const int hh = h + r - 1;
            short4v v = {0, 0, 0, 0};
            if (hh >= 0 && hh < H_)
                v = *reinterpret_cast<const short4v*>(
                    &xbase[(size_t)(ci0 + ci) * HW_ + hh * W_ + wq * 4]);
            pv[it] = v;
        }
    };
    auto lwrite = [&](int bufi) {
#pragma unroll
        for (int it = 0; it < 3; ++it) {
            const int idx = it * 512 + t;
            const int r = idx >> 9, ci = (idx >> 4) & 31, wq = idx & 15;
            Xs[bufi][r][1 + wq * 4 + 0][ci] = pv[it][0];
            Xs[bufi][r][1 + wq * 4 + 1][ci] = pv[it][1];
            Xs[bufi][r][1 + wq * 4 + 2][ci] = pv[it][2];
            Xs[bufi][r][1 + wq * 4 + 3][ci] = pv[it][3];
        }
    };

    gload(0);
    lwrite(0);           // compiler inserts vmcnt wait for pv
    __syncthreads();     // buf 0 + halo zeros visible

    for (int cb = 0; cb < 8; ++cb) {
        const int cur = cb & 1;
        if (cb < 7) gload(cb + 1);      // issue early; latency hides under taps

#pragma unroll 3
        for (int tap = 0; tap < 9; ++tap) {
            const int dh = tap / 3;
            const int dw = tap % 3;
            const short8* wp = wbP + ((size_t)(tap * 8 + cb)) * 1024 + lane;
            short8 af[2];
            af[0] = wp[(cot0 + 0) * 64];
            af[1] = wp[(cot0 + 1) * 64];
            short8 bf[4];
#pragma unroll
            for (int nt = 0; nt < 4; ++nt)
                bf[nt] = *reinterpret_cast<const short8*>(
                    &Xs[cur][dh][nt * 16 + lm + dw][lq * 8]);
#pragma unroll
            for (int nt = 0; nt < 4; ++nt)
#pragma unroll
                for (int ct = 0; ct < 2; ++ct)
                    acc[nt][ct] = __builtin_amdgcn_mfma_f32_16x16x32_bf16(
                        af[ct], bf[nt], acc[nt][ct], 0, 0, 0);
        }

        if (cb < 7) lwrite(cur ^ 1);    // vmcnt wait for pv, write other buffer
        __syncthreads();                // writes visible; readers of cur done
    }

#pragma unroll
    for (int nt = 0; nt < 4; ++nt) {
        const int pos = h * W_ + nt * 16 + lm;
#pragma unroll
        for (int ct = 0; ct < 2; ++ct) {
            const int co = cobase + ct * 16 + lq * 4;
#pragma unroll
            for (int r = 0; r < 4; ++r) {
                const float v = acc[nt][ct][r] + bias[co + r];
                if constexpr (std::is_same<OT, __hip_bfloat16>::value)
                    out[((size_t)(b * C_ + co + r)) * HW_ + pos] = __float2bfloat16(v);
                else
                    out[((size_t)(b * C_ + co + r)) * HW_ + pos] = v;
            }
        }
    }
}

// ---------------------------------------------------------------------------
// K3: fused attention. R10 structure (unchanged): one block per (b, 128-n
// stripe), grid 256, all 64 mt per block, double-buffered XT/XB via
// global_load_lds with counted vmcnt, S^T 2m x 4n wave split, fragment-
// linear Ps. 2 barriers/iter. LDS 114.7 KB, 1 block/CU. b == XCD.
// ---------------------------------------------------------------------------
__global__ __launch_bounds__(512, 2) void k_attn_mfma(
    const short8* __restrict__ xtPh, const short8* __restrict__ xtPl,
    const short8* __restrict__ xcPh, const short8* __restrict__ xcPl,
    const short8* __restrict__ xbP, float* __restrict__ O,
    float* __restrict__ Z)
{
    extern __shared__ __align__(16) char smem[];
    short8* XTs = (short8*)smem;                    // [2][1024]  (2 x 16 KB)
    short8* XBs = (short8*)(smem + 32768);          // [2][2048]  (2 x 32 KB)
    short8* Ps8 = (short8*)(smem + 98304);          // [8 T][2 mh][64]  16 KB
    short4v* Ps4 = (short4v*)(smem + 98304);
    float* zred = (float*)(smem + 114688);

    const int lin = blockIdx.x;                 // 0..255
    const int b = lin & 7, nblk = lin >> 3;     // b == XCD (round-robin dispatch)
    const int n0 = nblk * 128;

    const int t = threadIdx.x, wv = t >> 6, lane = t & 63;
    const int lm = lane & 15, lq = lane >> 4;
    const int mh = wv >> 2, nq2 = wv & 3;       // S^T split: m-half x n-quarter
    const int nq = wv >> 2, cq = wv & 3;        // PV split: n-half x c-quarter

    // Hoisted S^T B-frags: xc for wave's 2 n-tiles (nq2*2, nq2*2+1)
    short8 cB2[2][2][2];   // [ntile][kc][hilo]
#pragma unroll
    for (int ntile = 0; ntile < 2; ++ntile) {
        const int gt = nblk * 8 + nq2 * 2 + ntile;
        const size_t base = ((size_t)(b * 256 + gt) * 2) * 64 + lane;
        cB2[ntile][0][0] = xcPh[base];
        cB2[ntile][1][0] = xcPh[base + 64];
        cB2[ntile][0][1] = xcPl[base];
        cB2[ntile][1][1] = xcPl[base + 64];
    }
    asm volatile("s_waitcnt vmcnt(0)" ::: "memory");   // clean slate for counts

    auto stage = [&](int smt, int bufi) {
        short8* XT = XTs + bufi * 1024;
        short8* XB = XBs + bufi * 2048;
        const size_t abase = ((size_t)(b * 512 + smt * 8)) * 64;
#pragma unroll
        for (int k = 0; k < 2; ++k) {            // 2 xt chunks (issued FIRST)
            const int c = wv * 2 + k, ms = c >> 2, part = c & 3;
            const short8* src = (part < 2 ? xtPh : xtPl)
                                + abase + ms * 128 + (part & 1) * 64 + lane;
            GLL16(src, XT + c * 64);
        }
        const size_t p8 = ((size_t)(b * 2048 + smt * 32)) * 64;
#pragma unroll
        for (int k = 0; k < 4; ++k) {            // 4 xb chunks
            const int e = k * 512 + wv * 64;
            GLL16(xbP + p8 + e + lane, XB + e);
        }
    };
    stage(0, 0);                                 // prologue: 6 loads in flight

    f32x4 acc[4][4];   // O partial [n-subtile within half][c-tile within quarter]
#pragma unroll
    for (int i = 0; i < 4; ++i)
#pragma unroll
        for (int jj = 0; jj < 4; ++jj) acc[i][jj] = f32x4{0.f, 0.f, 0.f, 0.f};
    float zp = 0.f;

    for (int mt = 0; mt < 64; ++mt) {
        const int cur = mt & 1;
        // own cur-xt (oldest 2 of 6) landed; cur-xb still in flight
        asm volatile("s_waitcnt vmcnt(4)" ::: "memory");
        __builtin_amdgcn_sched_barrier(0);
        __builtin_amdgcn_s_barrier();            // all waves' xt staged; all
        __builtin_amdgcn_sched_barrier(0);       // finished prev PV reads
        // issue next tile's 6 loads into the other buffer (wrap keeps counts
        // uniform; final wrap-stage is harmless)
        stage((mt + 1) & 63, cur ^ 1);

        // ---- S^T: wave = (mh, nq2) -> 32 m x 32 n of this mt's 64x128 ----
        const short8* XT = XTs + cur * 1024;
#pragma unroll
        for (int ms2 = 0; ms2 < 2; ++ms2) {
            const int ms = mh * 2 + ms2;
            const short8 aH0 = XT[(ms * 4 + 0) * 64 + lane];
            const short8 aH1 = XT[(ms * 4 + 1) * 64 + lane];
            const short8 aL0 = XT[(ms * 4 + 2) * 64 + lane];
            const short8 aL1 = XT[(ms * 4 + 3) * 64 + lane];
#pragma unroll
            for (int ntile = 0; ntile < 2; ++ntile) {
                f32x4 s = {0.f, 0.f, 0.f, 0.f};
                __builtin_amdgcn_s_setprio(1);
                s = __builtin_amdgcn_mfma_f32_16x16x32_bf16(aH0, cB2[ntile][0][0], s, 0, 0, 0);
                s = __builtin_amdgcn_mfma_f32_16x16x32_bf16(aH1, cB2[ntile][1][0], s, 0, 0, 0);
                s = __builtin_amdgcn_mfma_f32_16x16x32_bf16(aH0, cB2[ntile][0][1], s, 0, 0, 0);
                s = __builtin_amdgcn_mfma_f32_16x16x32_bf16(aH1, cB2[ntile][1][1], s, 0, 0, 0);
                s = __builtin_amdgcn_mfma_f32_16x16x32_bf16(aL0, cB2[ntile][0][0], s, 0, 0, 0);
                s = __builtin_amdgcn_mfma_f32_16x16x32_bf16(aL1, cB2[ntile][1][0], s, 0, 0, 0);
                __builtin_amdgcn_s_setprio(0);
                const float e0 = __expf(s[0]), e1 = __expf(s[1]);
                const float e2 = __expf(s[2]), e3 = __expf(s[3]);
                zp += (e0 + e1) + (e2 + e3);
                short4v pk = { bfbits(e0), bfbits(e1), bfbits(e2), bfbits(e3) };
                // n = T*16+lm, m = ms*16+lq*4  ->  [T][mh][lqp*16+lm] + (lq&1)*8B
                const int T = nq2 * 2 + ntile;
                const int lqp = (ms & 1) * 2 + (lq >> 1);
                Ps4[(((T * 2 + mh) * 64) + lqp * 16 + lm) * 2 + (lq & 1)] = pk;
            }
        }
        // cur-xb (oldest 4 of 10) landed; next tile's 6 stay in flight.
        // lgkmcnt(0): own Ps writes visible before signaling.
        asm volatile("s_waitcnt vmcnt(6) lgkmcnt(0)" ::: "memory");
        __builtin_amdgcn_sched_barrier(0);
        __builtin_amdgcn_s_barrier();            // XB[cur] + all Ps visible
        __builtin_amdgcn_sched_barrier(0);

        // ---- PV: wave = (nq, cq) -> 64 n x 64 c, conflict-free frag reads ----
        const short8* XB = XBs + cur * 2048;
        short8 vb0[4], vb1[4];
#pragma unroll
        for (int q4 = 0; q4 < 4; ++q4) {
            const int ct = cq * 4 + q4;
            vb0[q4] = XB[ct * 64 + lane];
            vb1[q4] = XB[1024 + ct * 64 + lane];
        }
#pragma unroll
        for (int nt2 = 0; nt2 < 4; ++nt2) {
            const int T = nq * 4 + nt2;
            const short8 pa0 = Ps8[(T * 2 + 0) * 64 + lane];
            const short8 pa1 = Ps8[(T * 2 + 1) * 64 + lane];
            __builtin_amdgcn_s_setprio(1);
#pragma unroll
            for (int q4 = 0; q4 < 4; ++q4) {
                acc[nt2][q4] = __builtin_amdgcn_mfma_f32_16x16x32_bf16(
                    pa0, vb0[q4], acc[nt2][q4], 0, 0, 0);
                acc[nt2][q4] = __builtin_amdgcn_mfma_f32_16x16x32_bf16(
                    pa1, vb1[q4], acc[nt2][q4], 0, 0, 0);
            }
            __builtin_amdgcn_s_setprio(0);
        }
    }

    // Z: block reduction -> one atomicAdd
#pragma unroll
    for (int o = 32; o > 0; o >>= 1) zp += __shfl_down(zp, o, 64);
    if (lane == 0) zred[wv] = zp;
    __syncthreads();
    if (t == 0) {
        float zs = 0.f;
#pragma unroll
        for (int wvi = 0; wvi < 8; ++wvi) zs += zred[wvi];
        atomicAdd(&Z[b], zs);
    }

    // O direct stores (sole writer of this (b, n-stripe))
#pragma unroll
    for (int nt2 = 0; nt2 < 4; ++nt2) {
#pragma unroll
        for (int q4 = 0; q4 < 4; ++q4) {
            const int c = cq * 64 + q4 * 16 + lm;
#pragma unroll
            for (int r = 0; r < 4; ++r) {
                const int n = n0 + (nq * 4 + nt2) * 16 + lq * 4 + r;
                O[((size_t)b * HW_ + n) * C_ + c] = acc[nt2][q4][r];
            }
        }
    }
}

// ---------------------------------------------------------------------------
// K4: yB = bf16(x + O*(1/Z[b])) (flat reinterpretation add, bf16 output).
// ---------------------------------------------------------------------------
__global__ __launch_bounds__(256) void k_add_bf16(
    const float* __restrict__ x, const float* __restrict__ o,
    const float* __restrict__ Z, short4v* __restrict__ yB)
{
    const int bidx = blockIdx.x;
    const float invZ = 1.0f / Z[bidx >> 10];
    const size_t i = ((size_t)bidx * 256 + threadIdx.x) * 4;
    const float4 a = *reinterpret_cast<const float4*>(&x[i]);
    const float4 b = *reinterpret_cast<const float4*>(&o[i]);
    short4v r{bfbits(fmaf(b.x, invZ, a.x)), bfbits(fmaf(b.y, invZ, a.y)),
              bfbits(fmaf(b.z, invZ, a.z)), bfbits(fmaf(b.w, invZ, a.w))};
    yB[i >> 2] = r;
}

extern "C" void kernel_launch(void* const* d_in, const int* in_sizes, int n_in,
                              void* d_out, int out_size, void* d_ws, size_t ws_size,
                              hipStream_t stream)
{
    const float* x   = (const float*)d_in[0];
    const float* wt  = (const float*)d_in[1];
    const float* bt  = (const float*)d_in[2];
    const float* wc  = (const float*)d_in[3];
    const float* bc  = (const float*)d_in[4];
    const float* wbo = (const float*)d_in[5];
    const float* bbo = (const float*)d_in[6];
    const float* wo  = (const float*)d_in[7];
    const float* bo  = (const float*)d_in[8];
    float* out = (float*)d_out;

    uint8_t* w8 = (uint8_t*)d_ws;
    const size_t MB = 1u << 20;
    // [0,16): xtP/xcP (attn inputs; dead after attn)
    // [16,32): xbB bf16 (conv1 out; dead after pack_xb) -> yB after attn
    // [32,48): xbP (dead after attn) -> Wb2 overlays after attn
    // [48,80): O (attn out); Wb1 at 48 (dead before attn); xB at [64,80)
    //          (read only by conv1, which completes before attn writes O)
    short8* xtPh = (short8*)(w8);
    short8* xtPl = (short8*)(w8 + 4 * MB);
    short8* xcPh = (short8*)(w8 + 8 * MB);
    short8* xcPl = (short8*)(w8 + 12 * MB);
    __hip_bfloat16* xbB = (__hip_bfloat16*)(w8 + 16 * MB);
    short8* xbP  = (short8*)(w8 + 32 * MB);
    float*  O    = (float*)(w8 + 48 * MB);
    short8* Wb1  = (short8*)(w8 + 48 * MB);   // inside O region (dead before attn)
    short8* xB   = (short8*)(w8 + 64 * MB);   // bf16 x copy (conv1 staging input)
    short8* Wb2  = (short8*)(w8 + 32 * MB);   // inside xbP region (dead after attn)
    short4v* yB  = (short4v*)(w8 + 16 * MB);  // bf16 residual sum (conv2 input)
    float*  Z    = (float*)(w8 + 80 * MB);

    hipMemsetAsync(Z, 0, B_ * sizeof(float), stream);
    k_prep_w<<<dim3(288), 256, 0, stream>>>(wbo, Wb1);
    k_cvt_bf16<<<dim3(2048), 256, 0, stream>>>(x, xB);
    k_conv1x1<<<dim3(16, 4, 8), 256, 0, stream>>>(x, wt, bt, wc, bc,
                                                  xtPh, xtPl, xcPh, xcPl);
    k_conv3x3_mfma<__hip_bfloat16><<<dim3(512), 512, 0, stream>>>(
        (const short*)xB, Wb1, bbo, xbB);
    k_pack_xb<<<dim3(4096), 256, 0, stream>>>(xbB, xbP);
    k_attn_mfma<<<dim3(256), dim3(512), 114720, stream>>>(xtPh, xtPl, xcPh, xcPl,
                                                          xbP, O, Z);
    k_prep_w<<<dim3(288), 256, 0, stream>>>(wo, Wb2);
    k_add_bf16<<<dim3(8192), 256, 0, stream>>>(x, O, Z, yB);
    k_conv3x3_mfma<float><<<dim3(512), 512, 0, stream>>>(
        (const short*)yB, Wb2, bo, out);
}

// Round 9
// 364.450 us; speedup vs baseline: 1.1450x; 1.1450x over previous
//
#include <hip/hip_runtime.h>
#include <hip/hip_bf16.h>
#include <type_traits>

constexpr int B_ = 8, C_ = 256, P_ = 64, H_ = 64, W_ = 64, HW_ = 4096;

typedef __attribute__((ext_vector_type(8))) short short8;   // 8 bf16
typedef __attribute__((ext_vector_type(4))) short short4v;  // 4 bf16 (8 B)
typedef __attribute__((ext_vector_type(4))) float f32x4;

__device__ __forceinline__ short bfbits(float f) {
    __hip_bfloat16 h = __float2bfloat16(f);
    return *reinterpret_cast<short*>(&h);
}
__device__ __forceinline__ float bf2f(short s) {
    __hip_bfloat16 h = *reinterpret_cast<__hip_bfloat16*>(&s);
    return (float)h;
}

// async global->LDS, 16B per lane; dst must be wave-uniform base (HW adds lane*16)
#define GLL16(gsrc, ldst)                                                      \
    __builtin_amdgcn_global_load_lds(                                         \
        (const __attribute__((address_space(1))) void*)(gsrc),                \
        (__attribute__((address_space(3))) void*)(ldst), 16, 0, 0)

// ---------------------------------------------------------------------------
// Fragment-linear packed layouts (one wave-load = base + lane*16, contiguous):
//   xtP/xcP [b][tile16][kc2][lane64]x16B : chunk = x[row=tile*16+lm][p=kc*32+lq*8..+8]
//   xbP     [b][g128][ct16][lane64]x16B  : chunk = xb[c=ct*16+lm][m=g*32+lq*8..+8]
//   wbP     [tap9][cb8][cot16][lane64]x16B: chunk = w[co=cot*16+lm][ci=cb*32+lq*8..+8]
//   w1P     [conv2][pt4][kc8][hl2][lane64]x16B: chunk = w[p=pt*16+lm][c=kc*32+lq*8..+8]
// ---------------------------------------------------------------------------

// K0: weight prep, fp32 OIHW -> fragment-linear bf16 wbP. 288 blocks.
__global__ __launch_bounds__(256) void k_prep_w(
    const float* __restrict__ w, short8* __restrict__ wbP)
{
    const int idx = blockIdx.x * 256 + threadIdx.x;      // < 9*8*16*64 = 73728
    const int lane = idx & 63, cot = (idx >> 6) & 15;
    const int cb = (idx >> 10) & 7, tap = idx >> 13;
    const int lm = lane & 15, lq = lane >> 4;
    const int co = cot * 16 + lm, ci0 = cb * 32 + lq * 8;
    short8 v;
#pragma unroll
    for (int k = 0; k < 8; ++k)
        v[k] = bfbits(w[(co * 256 + ci0 + k) * 9 + tap]);
    wbP[idx] = v;
}

// K0d: 1x1-conv weight prep: w_top/w_cen fp32 [64][256] -> hi/lo fragment-
// linear A-frags w1P. 16 blocks (4096 threads, one chunk-pair each).
__global__ __launch_bounds__(256) void k_prep_w1(
    const float* __restrict__ wt, const float* __restrict__ wc,
    short8* __restrict__ w1P)
{
    const int idx = blockIdx.x * 256 + threadIdx.x;      // < 4096
    const int lane = idx & 63, kc = (idx >> 6) & 7;
    const int pt = (idx >> 9) & 3, conv = idx >> 11;
    const int lm = lane & 15, lq = lane >> 4;
    const float* w = conv ? wc : wt;
    const float* wp = w + (pt * 16 + lm) * C_ + kc * 32 + lq * 8;
    short8 vh, vl;
#pragma unroll
    for (int k = 0; k < 8; ++k) {
        const float v = wp[k];
        const short h = bfbits(v);
        vh[k] = h;
        vl[k] = bfbits(v - bf2f(h));
    }
    const size_t o = (((size_t)(conv * 4 + pt) * 8 + kc) * 2) * 64 + lane;
    w1P[o] = vh;
    w1P[o + 64] = vl;
}

// K0c: fp32 [B][C][HW] -> bf16 same-order copy (conv3x3 staging input).
// 2048 blocks; thread: 4 float4 loads -> 2 short8 stores (16 elems).
__global__ __launch_bounds__(256) void k_cvt_bf16(
    const float* __restrict__ x, short8* __restrict__ xB)
{
    const size_t i = ((size_t)blockIdx.x * 256 + threadIdx.x) * 16;
    short8 o[2];
#pragma unroll
    for (int q = 0; q < 2; ++q) {
#pragma unroll
        for (int j = 0; j < 2; ++j) {
            const float4 v = *reinterpret_cast<const float4*>(&x[i + q * 8 + j * 4]);
            o[q][j * 4 + 0] = bfbits(v.x);
            o[q][j * 4 + 1] = bfbits(v.y);
            o[q][j * 4 + 2] = bfbits(v.z);
            o[q][j * 4 + 3] = bfbits(v.w);
        }
    }
    short8* dp = (short8*)&xB[i >> 3];
    dp[0] = o[0];
    dp[1] = o[1];
}

// K0b: xb [B][C][HW] bf16 -> fragment-linear xbP. 4096 blocks.
__global__ __launch_bounds__(256) void k_pack_xb(
    const __hip_bfloat16* __restrict__ xb, short8* __restrict__ xbP)
{
    const int tid = blockIdx.x * 256 + threadIdx.x;
    const int lane = tid & 63, wid = tid >> 6;           // wid < 8*128*16
    const int ct = wid & 15, g = (wid >> 4) & 127, b = wid >> 11;
    const int c = ct * 16 + (lane >> 2);
    const int mo = g * 32 + (lane & 3) * 8;
    const short8 v = *reinterpret_cast<const short8*>(
        &xb[((size_t)(b * 256 + c)) * HW_ + mo]);
    xbP[(size_t)wid * 64 + (lane & 3) * 16 + (lane >> 2)] = v;
}

// ---------------------------------------------------------------------------
// K1: 1x1 convs, R15: MFMA implementation. One wave per n-tile (16 n), both
// convs + all 64 p per wave. Hi/lo on BOTH operands, 3 products (hh, hl, lh;
// wl*xl ~2^-18 dropped — same trick as attn S^T). x read ONCE (was 8x);
// the 8.6 GFLOP moves from the 157 TF fp32 VALU (>=55us floor) to MFMA.
// Epilogue writes hi/lo outputs directly into fragment-linear xtP/xcP via
// the D->fragment lane mapping (tl=(pt&1)*2+(lq>>1), off=(lq&1)*4+r).
// Grid (64, 8) x 256 threads.
// ---------------------------------------------------------------------------
__global__ __launch_bounds__(256) void k_conv1x1_mfma(
    const float* __restrict__ x, const short8* __restrict__ w1P,
    const float* __restrict__ b_top, const float* __restrict__ b_cen,
    short4v* __restrict__ xtPh, short4v* __restrict__ xtPl,
    short4v* __restrict__ xcPh, short4v* __restrict__ xcPl)
{
    const int b = blockIdx.y;
    const int t = threadIdx.x, wv = t >> 6, lane = t & 63;
    const int lm = lane & 15, lq = lane >> 4;
    const int nt = blockIdx.x * 4 + wv;
    const float* xp = x + (size_t)b * C_ * HW_ + nt * 16 + lm;

    f32x4 acc[2][4];   // [conv][p-tile]
#pragma unroll
    for (int i = 0; i < 2; ++i)
#pragma unroll
        for (int j = 0; j < 4; ++j) acc[i][j] = f32x4{0.f, 0.f, 0.f, 0.f};

    for (int kc = 0; kc < 8; ++kc) {
        // B-frag: lane = x[c = kc*32+lq*8 .. +8][n = nt*16+lm], hi/lo in-reg
        short8 bh, bl;
#pragma unroll
        for (int k = 0; k < 8; ++k) {
            const float v = xp[(size_t)(kc * 32 + lq * 8 + k) * HW_];
            const short h = bfbits(v);
            bh[k] = h;
            bl[k] = bfbits(v - bf2f(h));
        }
#pragma unroll
        for (int conv = 0; conv < 2; ++conv)
#pragma unroll
            for (int pt = 0; pt < 4; ++pt) {
                const size_t o =
                    (((size_t)(conv * 4 + pt) * 8 + kc) * 2) * 64 + lane;
                const short8 ah = w1P[o];
                const short8 al = w1P[o + 64];
                f32x4 a = acc[conv][pt];
                a = __builtin_amdgcn_mfma_f32_16x16x32_bf16(ah, bh, a, 0, 0, 0);
                a = __builtin_amdgcn_mfma_f32_16x16x32_bf16(ah, bl, a, 0, 0, 0);
                a = __builtin_amdgcn_mfma_f32_16x16x32_bf16(al, bh, a, 0, 0, 0);
                acc[conv][pt] = a;
            }
    }

    // Epilogue: D lane (lm,lq) holds p = pt*16 + lq*4 + r, n = nt*16 + lm.
    // Fragment target: kc = pt>>1, tl = (pt&1)*2 + (lq>>1), shortoff = (lq&1)*4.
#pragma unroll
    for (int conv = 0; conv < 2; ++conv) {
        const float* bias = conv ? b_cen : b_top;
        short4v* oh = conv ? xcPh : xtPh;
        short4v* ol = conv ? xcPl : xtPl;
#pragma unroll
        for (int pt = 0; pt < 4; ++pt) {
            const int kc = pt >> 1;
            const int tl = (pt & 1) * 2 + (lq >> 1);
            const size_t c16 = ((size_t)(b * 256 + nt) * 2 + kc) * 64 + tl * 16 + lm;
            short4v vh, vl;
#pragma unroll
            for (int r = 0; r < 4; ++r) {
                const float v = acc[conv][pt][r] + bias[pt * 16 + lq * 4 + r];
                const short h = bfbits(v);
                vh[r] = h;
                vl[r] = bfbits(v - bf2f(h));
            }
            oh[c16 * 2 + (lq & 1)] = vh;
            ol[c16 * 2 + (lq & 1)] = vl;
        }
    }
}

// ---------------------------------------------------------------------------
// K2/K5: 3x3 conv as implicit GEMM, bf16 MFMA. R13 structure (merged
// co-halves, 512-thread blocks, grid 512 1D, b==XCD, lane->w coalesced
// staging) with BF16 INPUT: staging reads short4v (8B/lane) and stores raw
// bf16 bits -> zero cvt instructions in the hot loop.
// ---------------------------------------------------------------------------
template <typename OT>
__global__ __launch_bounds__(512, 4) void k_conv3x3_mfma(
    const short* __restrict__ xin, const short8* __restrict__ wbP,
    const float* __restrict__ bias, OT* __restrict__ out)
{
    __shared__ __align__(16) short Xs[3][66][40];
    const int lin = blockIdx.x;                 // 0..511
    const int b = lin & 7, h = lin >> 3;        // b == XCD
    const int t = threadIdx.x;
    const int wave = t >> 6, lane = t & 63;
    const int lm = lane & 15, lq = lane >> 4;
    const int cobase = wave * 32;
    const int cot0 = wave * 2;                  // co-tile index base (co/16)

    f32x4 acc[4][2];   // [n_tile][co_tile]
#pragma unroll
    for (int i = 0; i < 4; ++i)
#pragma unroll
        for (int j = 0; j < 2; ++j) acc[i][j] = f32x4{0.f, 0.f, 0.f, 0.f};

    if (t < 192) {   // zero w-halo columns once (3 r x 2 sides x 32 ci)
        const int r = t >> 6, cc = t & 31, side = (t >> 5) & 1;
        Xs[r][side ? 65 : 0][cc] = 0;
    }

    const short* xbase = xin + (size_t)b * C_ * HW_;

    for (int cb = 0; cb < 8; ++cb) {
        const int ci0 = cb * 32;
        __syncthreads();
        // stage 3 rows x 32 ci x 64 w: 1536 short4 over 512 threads.
        // idx -> (r, ci, wq); consecutive wq -> 128B coalesced segments.
#pragma unroll
        for (int it = 0; it < 3; ++it) {
            const int idx = it * 512 + t;
            const int r = idx >> 9, ci = (idx >> 4) & 31, wq = idx & 15;
            const int hh = h + r - 1;
            short4v v = {0, 0, 0, 0};
            if (hh >= 0 && hh < H_)
                v = *reinterpret_cast<const short4v*>(
                    &xbase[(size_t)(ci0 + ci) * HW_ + hh * W_ + wq * 4]);
            Xs[r][1 + wq * 4 + 0][ci] = v[0];
            Xs[r][1 + wq * 4 + 1][ci] = v[1];
            Xs[r][1 + wq * 4 + 2][ci] = v[2];
            Xs[r][1 + wq * 4 + 3][ci] = v[3];
        }
        __syncthreads();

#pragma unroll 3
        for (int tap = 0; tap < 9; ++tap) {
            const int dh = tap / 3;
            const int dw = tap % 3;
            const short8* wp = wbP + ((size_t)(tap * 8 + cb)) * 1024 + lane;
            short8 af[2];
            af[0] = wp[(cot0 + 0) * 64];
            af[1] = wp[(cot0 + 1) * 64];
            short8 bf[4];
#pragma unroll
            for (int nt = 0; nt < 4; ++nt)
                bf[nt] = *reinterpret_cast<const short8*>(
                    &Xs[dh][nt * 16 + lm + dw][lq * 8]);
#pragma unroll
            for (int nt = 0; nt < 4; ++nt)
#pragma unroll
                for (int ct = 0; ct < 2; ++ct)
                    acc[nt][ct] = __builtin_amdgcn_mfma_f32_16x16x32_bf16(
                        af[ct], bf[nt], acc[nt][ct], 0, 0, 0);
        }
    }

#pragma unroll
    for (int nt = 0; nt < 4; ++nt) {
        const int pos = h * W_ + nt * 16 + lm;
#pragma unroll
        for (int ct = 0; ct < 2; ++ct) {
            const int co = cobase + ct * 16 + lq * 4;
#pragma unroll
            for (int r = 0; r < 4; ++r) {
                const float v = acc[nt][ct][r] + bias[co + r];
                if constexpr (std::is_same<OT, __hip_bfloat16>::value)
                    out[((size_t)(b * C_ + co + r)) * HW_ + pos] = __float2bfloat16(v);
                else
                    out[((size_t)(b * C_ + co + r)) * HW_ + pos] = v;
            }
        }
    }
}

// ---------------------------------------------------------------------------
// K3: fused attention. R10 structure (unchanged): one block per (b, 128-n
// stripe), grid 256, all 64 mt per block, double-buffered XT/XB via
// global_load_lds with counted vmcnt, S^T 2m x 4n wave split, fragment-
// linear Ps. 2 barriers/iter. LDS 114.7 KB, 1 block/CU. b == XCD.
// ---------------------------------------------------------------------------
__global__ __launch_bounds__(512, 2) void k_attn_mfma(
    const short8* __restrict__ xtPh, const short8* __restrict__ xtPl,
    const short8* __restrict__ xcPh, const short8* __restrict__ xcPl,
    const short8* __restrict__ xbP, float* __restrict__ O,
    float* __restrict__ Z)
{
    extern __shared__ __align__(16) char smem[];
    short8* XTs = (short8*)smem;                    // [2][1024]  (2 x 16 KB)
    short8* XBs = (short8*)(smem + 32768);          // [2][2048]  (2 x 32 KB)
    short8* Ps8 = (short8*)(smem + 98304);          // [8 T][2 mh][64]  16 KB
    short4v* Ps4 = (short4v*)(smem + 98304);
    float* zred = (float*)(smem + 114688);

    const int lin = blockIdx.x;                 // 0..255
    const int b = lin & 7, nblk = lin >> 3;     // b == XCD (round-robin dispatch)
    const int n0 = nblk * 128;

    const int t = threadIdx.x, wv = t >> 6, lane = t & 63;
    const int lm = lane & 15, lq = lane >> 4;
    const int mh = wv >> 2, nq2 = wv & 3;       // S^T split: m-half x n-quarter
    const int nq = wv >> 2, cq = wv & 3;        // PV split: n-half x c-quarter

    // Hoisted S^T B-frags: xc for wave's 2 n-tiles (nq2*2, nq2*2+1)
    short8 cB2[2][2][2];   // [ntile][kc][hilo]
#pragma unroll
    for (int ntile = 0; ntile < 2; ++ntile) {
        const int gt = nblk * 8 + nq2 * 2 + ntile;
        const size_t base = ((size_t)(b * 256 + gt) * 2) * 64 + lane;
        cB2[ntile][0][0] = xcPh[base];
        cB2[ntile][1][0] = xcPh[base + 64];
        cB2[ntile][0][1] = xcPl[base];
        cB2[ntile][1][1] = xcPl[base + 64];
    }
    asm volatile("s_waitcnt vmcnt(0)" ::: "memory");   // clean slate for counts

    auto stage = [&](int smt, int bufi) {
        short8* XT = XTs + bufi * 1024;
        short8* XB = XBs + bufi * 2048;
        const size_t abase = ((size_t)(b * 512 + smt * 8)) * 64;
#pragma unroll
        for (int k = 0; k < 2; ++k) {            // 2 xt chunks (issued FIRST)
            const int c = wv * 2 + k, ms = c >> 2, part = c & 3;
            const short8* src = (part < 2 ? xtPh : xtPl)
                                + abase + ms * 128 + (part & 1) * 64 + lane;
            GLL16(src, XT + c * 64);
        }
        const size_t p8 = ((size_t)(b * 2048 + smt * 32)) * 64;
#pragma unroll
        for (int k = 0; k < 4; ++k) {            // 4 xb chunks
            const int e = k * 512 + wv * 64;
            GLL16(xbP + p8 + e + lane, XB + e);
        }
    };
    stage(0, 0);                                 // prologue: 6 loads in flight

    f32x4 acc[4][4];   // O partial [n-subtile within half][c-tile within quarter]
#pragma unroll
    for (int i = 0; i < 4; ++i)
#pragma unroll
        for (int jj = 0; jj < 4; ++jj) acc[i][jj] = f32x4{0.f, 0.f, 0.f, 0.f};
    float zp = 0.f;

    for (int mt = 0; mt < 64; ++mt) {
        const int cur = mt & 1;
        // own cur-xt (oldest 2 of 6) landed; cur-xb still in flight
        asm volatile("s_waitcnt vmcnt(4)" ::: "memory");
        __builtin_amdgcn_sched_barrier(0);
        __builtin_amdgcn_s_barrier();            // all waves' xt staged; all
        __builtin_amdgcn_sched_barrier(0);       // finished prev PV reads
        // issue next tile's 6 loads into the other buffer (wrap keeps counts
        // uniform; final wrap-stage is harmless)
        stage((mt + 1) & 63, cur ^ 1);

        // ---- S^T: wave = (mh, nq2) -> 32 m x 32 n of this mt's 64x128 ----
        const short8* XT = XTs + cur * 1024;
#pragma unroll
        for (int ms2 = 0; ms2 < 2; ++ms2) {
            const int ms = mh * 2 + ms2;
            const short8 aH0 = XT[(ms * 4 + 0) * 64 + lane];
            const short8 aH1 = XT[(ms * 4 + 1) * 64 + lane];
            const short8 aL0 = XT[(ms * 4 + 2) * 64 + lane];
            const short8 aL1 = XT[(ms * 4 + 3) * 64 + lane];
#pragma unroll
            for (int ntile = 0; ntile < 2; ++ntile) {
                f32x4 s = {0.f, 0.f, 0.f, 0.f};
                __builtin_amdgcn_s_setprio(1);
                s = __builtin_amdgcn_mfma_f32_16x16x32_bf16(aH0, cB2[ntile][0][0], s, 0, 0, 0);
                s = __builtin_amdgcn_mfma_f32_16x16x32_bf16(aH1, cB2[ntile][1][0], s, 0, 0, 0);
                s = __builtin_amdgcn_mfma_f32_16x16x32_bf16(aH0, cB2[ntile][0][1], s, 0, 0, 0);
                s = __builtin_amdgcn_mfma_f32_16x16x32_bf16(aH1, cB2[ntile][1][1], s, 0, 0, 0);
                s = __builtin_amdgcn_mfma_f32_16x16x32_bf16(aL0, cB2[ntile][0][0], s, 0, 0, 0);
                s = __builtin_amdgcn_mfma_f32_16x16x32_bf16(aL1, cB2[ntile][1][0], s, 0, 0, 0);
                __builtin_amdgcn_s_setprio(0);
                const float e0 = __expf(s[0]), e1 = __expf(s[1]);
                const float e2 = __expf(s[2]), e3 = __expf(s[3]);
                zp += (e0 + e1) + (e2 + e3);
                short4v pk = { bfbits(e0), bfbits(e1), bfbits(e2), bfbits(e3) };
                // n = T*16+lm, m = ms*16+lq*4  ->  [T][mh][lqp*16+lm] + (lq&1)*8B
                const int T = nq2 * 2 + ntile;
                const int lqp = (ms & 1) * 2 + (lq >> 1);
                Ps4[(((T * 2 + mh) * 64) + lqp * 16 + lm) * 2 + (lq & 1)] = pk;
            }
        }
        // cur-xb (oldest 4 of 10) landed; next tile's 6 stay in flight.
        // lgkmcnt(0): own Ps writes visible before signaling.
        asm volatile("s_waitcnt vmcnt(6) lgkmcnt(0)" ::: "memory");
        __builtin_amdgcn_sched_barrier(0);
        __builtin_amdgcn_s_barrier();            // XB[cur] + all Ps visible
        __builtin_amdgcn_sched_barrier(0);

        // ---- PV: wave = (nq, cq) -> 64 n x 64 c, conflict-free frag reads ----
        const short8* XB = XBs + cur * 2048;
        short8 vb0[4], vb1[4];
#pragma unroll
        for (int q4 = 0; q4 < 4; ++q4) {
            const int ct = cq * 4 + q4;
            vb0[q4] = XB[ct * 64 + lane];
            vb1[q4] = XB[1024 + ct * 64 + lane];
        }
#pragma unroll
        for (int nt2 = 0; nt2 < 4; ++nt2) {
            const int T = nq * 4 + nt2;
            const short8 pa0 = Ps8[(T * 2 + 0) * 64 + lane];
            const short8 pa1 = Ps8[(T * 2 + 1) * 64 + lane];
            __builtin_amdgcn_s_setprio(1);
#pragma unroll
            for (int q4 = 0; q4 < 4; ++q4) {
                acc[nt2][q4] = __builtin_amdgcn_mfma_f32_16x16x32_bf16(
                    pa0, vb0[q4], acc[nt2][q4], 0, 0, 0);
                acc[nt2][q4] = __builtin_amdgcn_mfma_f32_16x16x32_bf16(
                    pa1, vb1[q4], acc[nt2][q4], 0, 0, 0);
            }
            __builtin_amdgcn_s_setprio(0);
        }
    }

    // Z: block reduction -> one atomicAdd
#pragma unroll
    for (int o = 32; o > 0; o >>= 1) zp += __shfl_down(zp, o, 64);
    if (lane == 0) zred[wv] = zp;
    __syncthreads();
    if (t == 0) {
        float zs = 0.f;
#pragma unroll
        for (int wvi = 0; wvi < 8; ++wvi) zs += zred[wvi];
        atomicAdd(&Z[b], zs);
    }

    // O direct stores (sole writer of this (b, n-stripe))
#pragma unroll
    for (int nt2 = 0; nt2 < 4; ++nt2) {
#pragma unroll
        for (int q4 = 0; q4 < 4; ++q4) {
            const int c = cq * 64 + q4 * 16 + lm;
#pragma unroll
            for (int r = 0; r < 4; ++r) {
                const int n = n0 + (nq * 4 + nt2) * 16 + lq * 4 + r;
                O[((size_t)b * HW_ + n) * C_ + c] = acc[nt2][q4][r];
            }
        }
    }
}

// ---------------------------------------------------------------------------
// K4: yB = bf16(x + O*(1/Z[b])) (flat reinterpretation add, bf16 output).
// ---------------------------------------------------------------------------
__global__ __launch_bounds__(256) void k_add_bf16(
    const float* __restrict__ x, const float* __restrict__ o,
    const float* __restrict__ Z, short4v* __restrict__ yB)
{
    const int bidx = blockIdx.x;
    const float invZ = 1.0f / Z[bidx >> 10];
    const size_t i = ((size_t)bidx * 256 + threadIdx.x) * 4;
    const float4 a = *reinterpret_cast<const float4*>(&x[i]);
    const float4 b = *reinterpret_cast<const float4*>(&o[i]);
    short4v r{bfbits(fmaf(b.x, invZ, a.x)), bfbits(fmaf(b.y, invZ, a.y)),
              bfbits(fmaf(b.z, invZ, a.z)), bfbits(fmaf(b.w, invZ, a.w))};
    yB[i >> 2] = r;
}

extern "C" void kernel_launch(void* const* d_in, const int* in_sizes, int n_in,
                              void* d_out, int out_size, void* d_ws, size_t ws_size,
                              hipStream_t stream)
{
    const float* x   = (const float*)d_in[0];
    const float* wt  = (const float*)d_in[1];
    const float* bt  = (const float*)d_in[2];
    const float* wc  = (const float*)d_in[3];
    const float* bc  = (const float*)d_in[4];
    const float* wbo = (const float*)d_in[5];
    const float* bbo = (const float*)d_in[6];
    const float* wo  = (const float*)d_in[7];
    const float* bo  = (const float*)d_in[8];
    float* out = (float*)d_out;

    uint8_t* w8 = (uint8_t*)d_ws;
    const size_t MB = 1u << 20;
    // [0,16): xtP/xcP (attn inputs; dead after attn)
    // [16,32): W1 (dead after conv1x1) -> xbB bf16 (conv3x3 out, dead after
    //          pack_xb) -> yB after attn
    // [32,48): xbP (dead after attn) -> Wb2 overlays after attn
    // [48,80): O (attn out); Wb1 at 48 (dead before attn); xB at [64,80)
    //          (read only by conv3x3 #1, which completes before attn writes O)
    short8* xtPh = (short8*)(w8);
    short8* xtPl = (short8*)(w8 + 4 * MB);
    short8* xcPh = (short8*)(w8 + 8 * MB);
    short8* xcPl = (short8*)(w8 + 12 * MB);
    short8* W1   = (short8*)(w8 + 16 * MB);   // 128 KB, dead after conv1x1
    __hip_bfloat16* xbB = (__hip_bfloat16*)(w8 + 16 * MB);
    short8* xbP  = (short8*)(w8 + 32 * MB);
    float*  O    = (float*)(w8 + 48 * MB);
    short8* Wb1  = (short8*)(w8 + 48 * MB);   // inside O region (dead before attn)
    short8* xB   = (short8*)(w8 + 64 * MB);   // bf16 x copy (conv3x3 #1 input)
    short8* Wb2  = (short8*)(w8 + 32 * MB);   // inside xbP region (dead after attn)
    short4v* yB  = (short4v*)(w8 + 16 * MB);  // bf16 residual sum (conv2 input)
    float*  Z    = (float*)(w8 + 80 * MB);

    hipMemsetAsync(Z, 0, B_ * sizeof(float), stream);
    k_prep_w<<<dim3(288), 256, 0, stream>>>(wbo, Wb1);
    k_prep_w1<<<dim3(16), 256, 0, stream>>>(wt, wc, W1);
    k_cvt_bf16<<<dim3(2048), 256, 0, stream>>>(x, xB);
    k_conv1x1_mfma<<<dim3(64, 8), 256, 0, stream>>>(
        x, W1, bt, bc, (short4v*)xtPh, (short4v*)xtPl,
        (short4v*)xcPh, (short4v*)xcPl);
    k_conv3x3_mfma<__hip_bfloat16><<<dim3(512), 512, 0, stream>>>(
        (const short*)xB, Wb1, bbo, xbB);
    k_pack_xb<<<dim3(4096), 256, 0, stream>>>(xbB, xbP);
    k_attn_mfma<<<dim3(256), dim3(512), 114720, stream>>>(xtPh, xtPl, xcPh, xcPl,
                                                          xbP, O, Z);
    k_prep_w<<<dim3(288), 256, 0, stream>>>(wo, Wb2);
    k_add_bf16<<<dim3(8192), 256, 0, stream>>>(x, O, Z, yB);
    k_conv3x3_mfma<float><<<dim3(512), 512, 0, stream>>>(
        (const short*)yB, Wb2, bo, out);
}

// Round 10
// 362.044 us; speedup vs baseline: 1.1526x; 1.0066x over previous
//
#include <hip/hip_runtime.h>
#include <hip/hip_bf16.h>
#include <type_traits>

constexpr int B_ = 8, C_ = 256, P_ = 64, H_ = 64, W_ = 64, HW_ = 4096;

typedef __attribute__((ext_vector_type(8))) short short8;   // 8 bf16
typedef __attribute__((ext_vector_type(4))) short short4v;  // 4 bf16 (8 B)
typedef __attribute__((ext_vector_type(4))) float f32x4;

__device__ __forceinline__ short bfbits(float f) {
    __hip_bfloat16 h = __float2bfloat16(f);
    return *reinterpret_cast<short*>(&h);
}
__device__ __forceinline__ float bf2f(short s) {
    __hip_bfloat16 h = *reinterpret_cast<__hip_bfloat16*>(&s);
    return (float)h;
}

// async global->LDS, 16B per lane; dst must be wave-uniform base (HW adds lane*16)
#define GLL16(gsrc, ldst)                                                      \
    __builtin_amdgcn_global_load_lds(                                         \
        (const __attribute__((address_space(1))) void*)(gsrc),                \
        (__attribute__((address_space(3))) void*)(ldst), 16, 0, 0)

// ---------------------------------------------------------------------------
// Fragment-linear packed layouts (one wave-load = base + lane*16, contiguous):
//   xtP/xcP [b][tile16][kc2][lane64]x16B : chunk = x[row=tile*16+lm][p=kc*32+lq*8..+8]
//   xbP     [b][g128][ct16][lane64]x16B  : chunk = xb[c=ct*16+lm][m=g*32+lq*8..+8]
//   wbP     [tap9][cb8][cot16][lane64]x16B: chunk = w[co=cot*16+lm][ci=cb*32+lq*8..+8]
//   w1P     [conv2][pt4][kc8][hl2][lane64]x16B: chunk = w[p=pt*16+lm][c=kc*32+lq*8..+8]
// ---------------------------------------------------------------------------

// K0: weight prep, fp32 OIHW -> fragment-linear bf16 wbP. 288 blocks.
__global__ __launch_bounds__(256) void k_prep_w(
    const float* __restrict__ w, short8* __restrict__ wbP)
{
    const int idx = blockIdx.x * 256 + threadIdx.x;      // < 9*8*16*64 = 73728
    const int lane = idx & 63, cot = (idx >> 6) & 15;
    const int cb = (idx >> 10) & 7, tap = idx >> 13;
    const int lm = lane & 15, lq = lane >> 4;
    const int co = cot * 16 + lm, ci0 = cb * 32 + lq * 8;
    short8 v;
#pragma unroll
    for (int k = 0; k < 8; ++k)
        v[k] = bfbits(w[(co * 256 + ci0 + k) * 9 + tap]);
    wbP[idx] = v;
}

// K0d: 1x1-conv weight prep: w_top/w_cen fp32 [64][256] -> hi/lo fragment-
// linear A-frags w1P. 16 blocks (4096 threads, one chunk-pair each).
__global__ __launch_bounds__(256) void k_prep_w1(
    const float* __restrict__ wt, const float* __restrict__ wc,
    short8* __restrict__ w1P)
{
    const int idx = blockIdx.x * 256 + threadIdx.x;      // < 4096
    const int lane = idx & 63, kc = (idx >> 6) & 7;
    const int pt = (idx >> 9) & 3, conv = idx >> 11;
    const int lm = lane & 15, lq = lane >> 4;
    const float* w = conv ? wc : wt;
    const float* wp = w + (pt * 16 + lm) * C_ + kc * 32 + lq * 8;
    short8 vh, vl;
#pragma unroll
    for (int k = 0; k < 8; ++k) {
        const float v = wp[k];
        const short h = bfbits(v);
        vh[k] = h;
        vl[k] = bfbits(v - bf2f(h));
    }
    const size_t o = (((size_t)(conv * 4 + pt) * 8 + kc) * 2) * 64 + lane;
    w1P[o] = vh;
    w1P[o + 64] = vl;
}

// K0c: fp32 [B][C][HW] -> bf16 same-order copy (conv3x3 staging input).
// 2048 blocks; thread: 4 float4 loads -> 2 short8 stores (16 elems).
__global__ __launch_bounds__(256) void k_cvt_bf16(
    const float* __restrict__ x, short8* __restrict__ xB)
{
    const size_t i = ((size_t)blockIdx.x * 256 + threadIdx.x) * 16;
    short8 o[2];
#pragma unroll
    for (int q = 0; q < 2; ++q) {
#pragma unroll
        for (int j = 0; j < 2; ++j) {
            const float4 v = *reinterpret_cast<const float4*>(&x[i + q * 8 + j * 4]);
            o[q][j * 4 + 0] = bfbits(v.x);
            o[q][j * 4 + 1] = bfbits(v.y);
            o[q][j * 4 + 2] = bfbits(v.z);
            o[q][j * 4 + 3] = bfbits(v.w);
        }
    }
    short8* dp = (short8*)&xB[i >> 3];
    dp[0] = o[0];
    dp[1] = o[1];
}

// K0b: xb [B][C][HW] bf16 -> fragment-linear xbP. 4096 blocks.
__global__ __launch_bounds__(256) void k_pack_xb(
    const __hip_bfloat16* __restrict__ xb, short8* __restrict__ xbP)
{
    const int tid = blockIdx.x * 256 + threadIdx.x;
    const int lane = tid & 63, wid = tid >> 6;           // wid < 8*128*16
    const int ct = wid & 15, g = (wid >> 4) & 127, b = wid >> 11;
    const int c = ct * 16 + (lane >> 2);
    const int mo = g * 32 + (lane & 3) * 8;
    const short8 v = *reinterpret_cast<const short8*>(
        &xb[((size_t)(b * 256 + c)) * HW_ + mo]);
    xbP[(size_t)wid * 64 + (lane & 3) * 16 + (lane >> 2)] = v;
}

// ---------------------------------------------------------------------------
// K1: 1x1 convs, R15 MFMA implementation (unchanged from R9).
// ---------------------------------------------------------------------------
__global__ __launch_bounds__(256) void k_conv1x1_mfma(
    const float* __restrict__ x, const short8* __restrict__ w1P,
    const float* __restrict__ b_top, const float* __restrict__ b_cen,
    short4v* __restrict__ xtPh, short4v* __restrict__ xtPl,
    short4v* __restrict__ xcPh, short4v* __restrict__ xcPl)
{
    const int b = blockIdx.y;
    const int t = threadIdx.x, wv = t >> 6, lane = t & 63;
    const int lm = lane & 15, lq = lane >> 4;
    const int nt = blockIdx.x * 4 + wv;
    const float* xp = x + (size_t)b * C_ * HW_ + nt * 16 + lm;

    f32x4 acc[2][4];   // [conv][p-tile]
#pragma unroll
    for (int i = 0; i < 2; ++i)
#pragma unroll
        for (int j = 0; j < 4; ++j) acc[i][j] = f32x4{0.f, 0.f, 0.f, 0.f};

    for (int kc = 0; kc < 8; ++kc) {
        // B-frag: lane = x[c = kc*32+lq*8 .. +8][n = nt*16+lm], hi/lo in-reg
        short8 bh, bl;
#pragma unroll
        for (int k = 0; k < 8; ++k) {
            const float v = xp[(size_t)(kc * 32 + lq * 8 + k) * HW_];
            const short h = bfbits(v);
            bh[k] = h;
            bl[k] = bfbits(v - bf2f(h));
        }
#pragma unroll
        for (int conv = 0; conv < 2; ++conv)
#pragma unroll
            for (int pt = 0; pt < 4; ++pt) {
                const size_t o =
                    (((size_t)(conv * 4 + pt) * 8 + kc) * 2) * 64 + lane;
                const short8 ah = w1P[o];
                const short8 al = w1P[o + 64];
                f32x4 a = acc[conv][pt];
                a = __builtin_amdgcn_mfma_f32_16x16x32_bf16(ah, bh, a, 0, 0, 0);
                a = __builtin_amdgcn_mfma_f32_16x16x32_bf16(ah, bl, a, 0, 0, 0);
                a = __builtin_amdgcn_mfma_f32_16x16x32_bf16(al, bh, a, 0, 0, 0);
                acc[conv][pt] = a;
            }
    }

    // Epilogue: D lane (lm,lq) holds p = pt*16 + lq*4 + r, n = nt*16 + lm.
    // Fragment target: kc = pt>>1, tl = (pt&1)*2 + (lq>>1), shortoff = (lq&1)*4.
#pragma unroll
    for (int conv = 0; conv < 2; ++conv) {
        const float* bias = conv ? b_cen : b_top;
        short4v* oh = conv ? xcPh : xtPh;
        short4v* ol = conv ? xcPl : xtPl;
#pragma unroll
        for (int pt = 0; pt < 4; ++pt) {
            const int kc = pt >> 1;
            const int tl = (pt & 1) * 2 + (lq >> 1);
            const size_t c16 = ((size_t)(b * 256 + nt) * 2 + kc) * 64 + tl * 16 + lm;
            short4v vh, vl;
#pragma unroll
            for (int r = 0; r < 4; ++r) {
                const float v = acc[conv][pt][r] + bias[pt * 16 + lq * 4 + r];
                const short h = bfbits(v);
                vh[r] = h;
                vl[r] = bfbits(v - bf2f(h));
            }
            oh[c16 * 2 + (lq & 1)] = vh;
            ol[c16 * 2 + (lq & 1)] = vl;
        }
    }
}

// ---------------------------------------------------------------------------
// K2/K5: 3x3 conv as implicit GEMM, bf16 MFMA. R16: h-PAIR blocks — 1024
// threads / 16 waves compute 128 n x 256 co (2 h rows), grid 256 1D with
// b==XCD. Halves per-output L2 weight traffic (590->295 MB: each block
// still reads the full 1.2 MB wbP but covers 2x output) AND per-output LDS
// bf reads AND barrier-drains. Wave = (nq, ch): row 2hp+nq, co-pair ch.
// Per tap: 2 af + 4 bf = 6 ops for 8 MFMA (same ratio as R13). acc 32 VGPR;
// __launch_bounds__(1024,4) keeps 4 waves/SIMD. LDS 21.1 KB single-buffer.
// ---------------------------------------------------------------------------
template <typename OT>
__global__ __launch_bounds__(1024, 4) void k_conv3x3_mfma(
    const short* __restrict__ xin, const short8* __restrict__ wbP,
    const float* __restrict__ bias, OT* __restrict__ out)
{
    __shared__ __align__(16) short Xs[4][66][40];
    const int lin = blockIdx.x;                 // 0..255
    const int b = lin & 7, hp = lin >> 3;       // b == XCD; hp = h-pair 0..31
    const int t = threadIdx.x;
    const int wave = t >> 6, lane = t & 63;
    const int lm = lane & 15, lq = lane >> 4;
    const int nq = wave >> 3, ch = wave & 7;    // row-half x co-pair

    f32x4 acc[4][2];   // [w_tile][co_tile]
#pragma unroll
    for (int i = 0; i < 4; ++i)
#pragma unroll
        for (int j = 0; j < 2; ++j) acc[i][j] = f32x4{0.f, 0.f, 0.f, 0.f};

    if (t < 256) {   // zero w-halo columns once (4 r x 2 sides x 32 ci)
        const int r = t >> 6, cc = t & 31, side = (t >> 5) & 1;
        Xs[r][side ? 65 : 0][cc] = 0;
    }

    const short* xbase = xin + (size_t)b * C_ * HW_;

    for (int cb = 0; cb < 8; ++cb) {
        const int ci0 = cb * 32;
        __syncthreads();
        // stage 4 rows x 32 ci x 64 w: 2048 short4 over 1024 threads.
        // idx -> (r, ci, wq); consecutive wq -> 128B coalesced segments.
#pragma unroll
        for (int it = 0; it < 2; ++it) {
            const int idx = it * 1024 + t;
            const int r = idx >> 9, ci = (idx >> 4) & 31, wq = idx & 15;
            const int hh = hp * 2 + r - 1;
            short4v v = {0, 0, 0, 0};
            if (hh >= 0 && hh < H_)
                v = *reinterpret_cast<const short4v*>(
                    &xbase[(size_t)(ci0 + ci) * HW_ + hh * W_ + wq * 4]);
            Xs[r][1 + wq * 4 + 0][ci] = v[0];
            Xs[r][1 + wq * 4 + 1][ci] = v[1];
            Xs[r][1 + wq * 4 + 2][ci] = v[2];
            Xs[r][1 + wq * 4 + 3][ci] = v[3];
        }
        __syncthreads();

#pragma unroll 3
        for (int tap = 0; tap < 9; ++tap) {
            const int dh = tap / 3;
            const int dw = tap % 3;
            const int slot = nq + dh;           // wave's input row for this tap
            const short8* wp = wbP + ((size_t)(tap * 8 + cb)) * 1024 + lane;
            short8 af[2];
            af[0] = wp[(ch * 2 + 0) * 64];
            af[1] = wp[(ch * 2 + 1) * 64];
            short8 bf[4];
#pragma unroll
            for (int wt = 0; wt < 4; ++wt)
                bf[wt] = *reinterpret_cast<const short8*>(
                    &Xs[slot][wt * 16 + lm + dw][lq * 8]);
#pragma unroll
            for (int wt = 0; wt < 4; ++wt)
#pragma unroll
                for (int ct = 0; ct < 2; ++ct)
                    acc[wt][ct] = __builtin_amdgcn_mfma_f32_16x16x32_bf16(
                        af[ct], bf[wt], acc[wt][ct], 0, 0, 0);
        }
    }

#pragma unroll
    for (int wt = 0; wt < 4; ++wt) {
        const int pos = (hp * 2 + nq) * W_ + wt * 16 + lm;
#pragma unroll
        for (int ct = 0; ct < 2; ++ct) {
            const int co = ch * 32 + ct * 16 + lq * 4;
#pragma unroll
            for (int r = 0; r < 4; ++r) {
                const float v = acc[wt][ct][r] + bias[co + r];
                if constexpr (std::is_same<OT, __hip_bfloat16>::value)
                    out[((size_t)(b * C_ + co + r)) * HW_ + pos] = __float2bfloat16(v);
                else
                    out[((size_t)(b * C_ + co + r)) * HW_ + pos] = v;
            }
        }
    }
}

// ---------------------------------------------------------------------------
// K3: fused attention. R10 structure (unchanged): one block per (b, 128-n
// stripe), grid 256, all 64 mt per block, double-buffered XT/XB via
// global_load_lds with counted vmcnt, S^T 2m x 4n wave split, fragment-
// linear Ps. 2 barriers/iter. LDS 114.7 KB, 1 block/CU. b == XCD.
// ---------------------------------------------------------------------------
__global__ __launch_bounds__(512, 2) void k_attn_mfma(
    const short8* __restrict__ xtPh, const short8* __restrict__ xtPl,
    const short8* __restrict__ xcPh, const short8* __restrict__ xcPl,
    const short8* __restrict__ xbP, float* __restrict__ O,
    float* __restrict__ Z)
{
    extern __shared__ __align__(16) char smem[];
    short8* XTs = (short8*)smem;                    // [2][1024]  (2 x 16 KB)
    short8* XBs = (short8*)(smem + 32768);          // [2][2048]  (2 x 32 KB)
    short8* Ps8 = (short8*)(smem + 98304);          // [8 T][2 mh][64]  16 KB
    short4v* Ps4 = (short4v*)(smem + 98304);
    float* zred = (float*)(smem + 114688);

    const int lin = blockIdx.x;                 // 0..255
    const int b = lin & 7, nblk = lin >> 3;     // b == XCD (round-robin dispatch)
    const int n0 = nblk * 128;

    const int t = threadIdx.x, wv = t >> 6, lane = t & 63;
    const int lm = lane & 15, lq = lane >> 4;
    const int mh = wv >> 2, nq2 = wv & 3;       // S^T split: m-half x n-quarter
    const int nq = wv >> 2, cq = wv & 3;        // PV split: n-half x c-quarter

    // Hoisted S^T B-frags: xc for wave's 2 n-tiles (nq2*2, nq2*2+1)
    short8 cB2[2][2][2];   // [ntile][kc][hilo]
#pragma unroll
    for (int ntile = 0; ntile < 2; ++ntile) {
        const int gt = nblk * 8 + nq2 * 2 + ntile;
        const size_t base = ((size_t)(b * 256 + gt) * 2) * 64 + lane;
        cB2[ntile][0][0] = xcPh[base];
        cB2[ntile][1][0] = xcPh[base + 64];
        cB2[ntile][0][1] = xcPl[base];
        cB2[ntile][1][1] = xcPl[base + 64];
    }
    asm volatile("s_waitcnt vmcnt(0)" ::: "memory");   // clean slate for counts

    auto stage = [&](int smt, int bufi) {
        short8* XT = XTs + bufi * 1024;
        short8* XB = XBs + bufi * 2048;
        const size_t abase = ((size_t)(b * 512 + smt * 8)) * 64;
#pragma unroll
        for (int k = 0; k < 2; ++k) {            // 2 xt chunks (issued FIRST)
            const int c = wv * 2 + k, ms = c >> 2, part = c & 3;
            const short8* src = (part < 2 ? xtPh : xtPl)
                                + abase + ms * 128 + (part & 1) * 64 + lane;
            GLL16(src, XT + c * 64);
        }
        const size_t p8 = ((size_t)(b * 2048 + smt * 32)) * 64;
#pragma unroll
        for (int k = 0; k < 4; ++k) {            // 4 xb chunks
            const int e = k * 512 + wv * 64;
            GLL16(xbP + p8 + e + lane, XB + e);
        }
    };
    stage(0, 0);                                 // prologue: 6 loads in flight

    f32x4 acc[4][4];   // O partial [n-subtile within half][c-tile within quarter]
#pragma unroll
    for (int i = 0; i < 4; ++i)
#pragma unroll
        for (int jj = 0; jj < 4; ++jj) acc[i][jj] = f32x4{0.f, 0.f, 0.f, 0.f};
    float zp = 0.f;

    for (int mt = 0; mt < 64; ++mt) {
        const int cur = mt & 1;
        // own cur-xt (oldest 2 of 6) landed; cur-xb still in flight
        asm volatile("s_waitcnt vmcnt(4)" ::: "memory");
        __builtin_amdgcn_sched_barrier(0);
        __builtin_amdgcn_s_barrier();            // all waves' xt staged; all
        __builtin_amdgcn_sched_barrier(0);       // finished prev PV reads
        // issue next tile's 6 loads into the other buffer (wrap keeps counts
        // uniform; final wrap-stage is harmless)
        stage((mt + 1) & 63, cur ^ 1);

        // ---- S^T: wave = (mh, nq2) -> 32 m x 32 n of this mt's 64x128 ----
        const short8* XT = XTs + cur * 1024;
#pragma unroll
        for (int ms2 = 0; ms2 < 2; ++ms2) {
            const int ms = mh * 2 + ms2;
            const short8 aH0 = XT[(ms * 4 + 0) * 64 + lane];
            const short8 aH1 = XT[(ms * 4 + 1) * 64 + lane];
            const short8 aL0 = XT[(ms * 4 + 2) * 64 + lane];
            const short8 aL1 = XT[(ms * 4 + 3) * 64 + lane];
#pragma unroll
            for (int ntile = 0; ntile < 2; ++ntile) {
                f32x4 s = {0.f, 0.f, 0.f, 0.f};
                __builtin_amdgcn_s_setprio(1);
                s = __builtin_amdgcn_mfma_f32_16x16x32_bf16(aH0, cB2[ntile][0][0], s, 0, 0, 0);
                s = __builtin_amdgcn_mfma_f32_16x16x32_bf16(aH1, cB2[ntile][1][0], s, 0, 0, 0);
                s = __builtin_amdgcn_mfma_f32_16x16x32_bf16(aH0, cB2[ntile][0][1], s, 0, 0, 0);
                s = __builtin_amdgcn_mfma_f32_16x16x32_bf16(aH1, cB2[ntile][1][1], s, 0, 0, 0);
                s = __builtin_amdgcn_mfma_f32_16x16x32_bf16(aL0, cB2[ntile][0][0], s, 0, 0, 0);
                s = __builtin_amdgcn_mfma_f32_16x16x32_bf16(aL1, cB2[ntile][1][0], s, 0, 0, 0);
                __builtin_amdgcn_s_setprio(0);
                const float e0 = __expf(s[0]), e1 = __expf(s[1]);
                const float e2 = __expf(s[2]), e3 = __expf(s[3]);
                zp += (e0 + e1) + (e2 + e3);
                short4v pk = { bfbits(e0), bfbits(e1), bfbits(e2), bfbits(e3) };
                // n = T*16+lm, m = ms*16+lq*4  ->  [T][mh][lqp*16+lm] + (lq&1)*8B
                const int T = nq2 * 2 + ntile;
                const int lqp = (ms & 1) * 2 + (lq >> 1);
                Ps4[(((T * 2 + mh) * 64) + lqp * 16 + lm) * 2 + (lq & 1)] = pk;
            }
        }
        // cur-xb (oldest 4 of 10) landed; next tile's 6 stay in flight.
        // lgkmcnt(0): own Ps writes visible before signaling.
        asm volatile("s_waitcnt vmcnt(6) lgkmcnt(0)" ::: "memory");
        __builtin_amdgcn_sched_barrier(0);
        __builtin_amdgcn_s_barrier();            // XB[cur] + all Ps visible
        __builtin_amdgcn_sched_barrier(0);

        // ---- PV: wave = (nq, cq) -> 64 n x 64 c, conflict-free frag reads ----
        const short8* XB = XBs + cur * 2048;
        short8 vb0[4], vb1[4];
#pragma unroll
        for (int q4 = 0; q4 < 4; ++q4) {
            const int ct = cq * 4 + q4;
            vb0[q4] = XB[ct * 64 + lane];
            vb1[q4] = XB[1024 + ct * 64 + lane];
        }
#pragma unroll
        for (int nt2 = 0; nt2 < 4; ++nt2) {
            const int T = nq * 4 + nt2;
            const short8 pa0 = Ps8[(T * 2 + 0) * 64 + lane];
            const short8 pa1 = Ps8[(T * 2 + 1) * 64 + lane];
            __builtin_amdgcn_s_setprio(1);
#pragma unroll
            for (int q4 = 0; q4 < 4; ++q4) {
                acc[nt2][q4] = __builtin_amdgcn_mfma_f32_16x16x32_bf16(
                    pa0, vb0[q4], acc[nt2][q4], 0, 0, 0);
                acc[nt2][q4] = __builtin_amdgcn_mfma_f32_16x16x32_bf16(
                    pa1, vb1[q4], acc[nt2][q4], 0, 0, 0);
            }
            __builtin_amdgcn_s_setprio(0);
        }
    }

    // Z: block reduction -> one atomicAdd
#pragma unroll
    for (int o = 32; o > 0; o >>= 1) zp += __shfl_down(zp, o, 64);
    if (lane == 0) zred[wv] = zp;
    __syncthreads();
    if (t == 0) {
        float zs = 0.f;
#pragma unroll
        for (int wvi = 0; wvi < 8; ++wvi) zs += zred[wvi];
        atomicAdd(&Z[b], zs);
    }

    // O direct stores (sole writer of this (b, n-stripe))
#pragma unroll
    for (int nt2 = 0; nt2 < 4; ++nt2) {
#pragma unroll
        for (int q4 = 0; q4 < 4; ++q4) {
            const int c = cq * 64 + q4 * 16 + lm;
#pragma unroll
            for (int r = 0; r < 4; ++r) {
                const int n = n0 + (nq * 4 + nt2) * 16 + lq * 4 + r;
                O[((size_t)b * HW_ + n) * C_ + c] = acc[nt2][q4][r];
            }
        }
    }
}

// ---------------------------------------------------------------------------
// K4: yB = bf16(x + O*(1/Z[b])) (flat reinterpretation add, bf16 output).
// ---------------------------------------------------------------------------
__global__ __launch_bounds__(256) void k_add_bf16(
    const float* __restrict__ x, const float* __restrict__ o,
    const float* __restrict__ Z, short4v* __restrict__ yB)
{
    const int bidx = blockIdx.x;
    const float invZ = 1.0f / Z[bidx >> 10];
    const size_t i = ((size_t)bidx * 256 + threadIdx.x) * 4;
    const float4 a = *reinterpret_cast<const float4*>(&x[i]);
    const float4 b = *reinterpret_cast<const float4*>(&o[i]);
    short4v r{bfbits(fmaf(b.x, invZ, a.x)), bfbits(fmaf(b.y, invZ, a.y)),
              bfbits(fmaf(b.z, invZ, a.z)), bfbits(fmaf(b.w, invZ, a.w))};
    yB[i >> 2] = r;
}

extern "C" void kernel_launch(void* const* d_in, const int* in_sizes, int n_in,
                              void* d_out, int out_size, void* d_ws, size_t ws_size,
                              hipStream_t stream)
{
    const float* x   = (const float*)d_in[0];
    const float* wt  = (const float*)d_in[1];
    const float* bt  = (const float*)d_in[2];
    const float* wc  = (const float*)d_in[3];
    const float* bc  = (const float*)d_in[4];
    const float* wbo = (const float*)d_in[5];
    const float* bbo = (const float*)d_in[6];
    const float* wo  = (const float*)d_in[7];
    const float* bo  = (const float*)d_in[8];
    float* out = (float*)d_out;

    uint8_t* w8 = (uint8_t*)d_ws;
    const size_t MB = 1u << 20;
    // [0,16): xtP/xcP (attn inputs; dead after attn)
    // [16,32): W1 (dead after conv1x1) -> xbB bf16 (conv3x3 out, dead after
    //          pack_xb) -> yB after attn
    // [32,48): xbP (dead after attn) -> Wb2 overlays after attn
    // [48,80): O (attn out); Wb1 at 48 (dead before attn); xB at [64,80)
    //          (read only by conv3x3 #1, which completes before attn writes O)
    short8* xtPh = (short8*)(w8);
    short8* xtPl = (short8*)(w8 + 4 * MB);
    short8* xcPh = (short8*)(w8 + 8 * MB);
    short8* xcPl = (short8*)(w8 + 12 * MB);
    short8* W1   = (short8*)(w8 + 16 * MB);   // 128 KB, dead after conv1x1
    __hip_bfloat16* xbB = (__hip_bfloat16*)(w8 + 16 * MB);
    short8* xbP  = (short8*)(w8 + 32 * MB);
    float*  O    = (float*)(w8 + 48 * MB);
    short8* Wb1  = (short8*)(w8 + 48 * MB);   // inside O region (dead before attn)
    short8* xB   = (short8*)(w8 + 64 * MB);   // bf16 x copy (conv3x3 #1 input)
    short8* Wb2  = (short8*)(w8 + 32 * MB);   // inside xbP region (dead after attn)
    short4v* yB  = (short4v*)(w8 + 16 * MB);  // bf16 residual sum (conv2 input)
    float*  Z    = (float*)(w8 + 80 * MB);

    hipMemsetAsync(Z, 0, B_ * sizeof(float), stream);
    k_prep_w<<<dim3(288), 256, 0, stream>>>(wbo, Wb1);
    k_prep_w1<<<dim3(16), 256, 0, stream>>>(wt, wc, W1);
    k_cvt_bf16<<<dim3(2048), 256, 0, stream>>>(x, xB);
    k_conv1x1_mfma<<<dim3(64, 8), 256, 0, stream>>>(
        x, W1, bt, bc, (short4v*)xtPh, (short4v*)xtPl,
        (short4v*)xcPh, (short4v*)xcPl);
    k_conv3x3_mfma<__hip_bfloat16><<<dim3(256), 1024, 0, stream>>>(
        (const short*)xB, Wb1, bbo, xbB);
    k_pack_xb<<<dim3(4096), 256, 0, stream>>>(xbB, xbP);
    k_attn_mfma<<<dim3(256), dim3(512), 114720, stream>>>(xtPh, xtPl, xcPh, xcPl,
                                                          xbP, O, Z);
    k_prep_w<<<dim3(288), 256, 0, stream>>>(wo, Wb2);
    k_add_bf16<<<dim3(8192), 256, 0, stream>>>(x, O, Z, yB);
    k_conv3x3_mfma<float><<<dim3(256), 1024, 0, stream>>>(
        (const short*)yB, Wb2, bo, out);
}